// Round 2
// baseline (904.651 us; speedup 1.0000x reference)
//
#include <hip/hip_runtime.h>
#include <math.h>

#define ROWS 65536
#define DIM  256
#define KC   1024
#define NQ   (ROWS * DIM)

// ---- ws layout (bytes) ----
// [0]      double lossacc
// [16]     int    counts[1024]        (ends 4112)
// [4224]   float  B32[1024]           (ends 8320)

// ---------------------------------------------------------------------------
// numpy pairwise sum-of-squares helpers (identical op order to the passing
// kernel: two 128-halves, 8 accumulators each, tree combine, halves added
// last; __fmul_rn/__fadd_rn forbid fma contraction).
// ---------------------------------------------------------------------------
__device__ __forceinline__ float half_sq_sum(const float* __restrict__ a) {
    float4 u0 = *(const float4*)(a);
    float4 u1 = *(const float4*)(a + 4);
    float r0 = __fmul_rn(u0.x, u0.x);
    float r1 = __fmul_rn(u0.y, u0.y);
    float r2 = __fmul_rn(u0.z, u0.z);
    float r3 = __fmul_rn(u0.w, u0.w);
    float r4 = __fmul_rn(u1.x, u1.x);
    float r5 = __fmul_rn(u1.y, u1.y);
    float r6 = __fmul_rn(u1.z, u1.z);
    float r7 = __fmul_rn(u1.w, u1.w);
    for (int i = 8; i < 128; i += 8) {
        float4 v0 = *(const float4*)(a + i);
        float4 v1 = *(const float4*)(a + i + 4);
        r0 = __fadd_rn(r0, __fmul_rn(v0.x, v0.x));
        r1 = __fadd_rn(r1, __fmul_rn(v0.y, v0.y));
        r2 = __fadd_rn(r2, __fmul_rn(v0.z, v0.z));
        r3 = __fadd_rn(r3, __fmul_rn(v0.w, v0.w));
        r4 = __fadd_rn(r4, __fmul_rn(v1.x, v1.x));
        r5 = __fadd_rn(r5, __fmul_rn(v1.y, v1.y));
        r6 = __fadd_rn(r6, __fmul_rn(v1.z, v1.z));
        r7 = __fadd_rn(r7, __fmul_rn(v1.w, v1.w));
    }
    float s01 = __fadd_rn(r0, r1);
    float s23 = __fadd_rn(r2, r3);
    float s45 = __fadd_rn(r4, r5);
    float s67 = __fadd_rn(r6, r7);
    return __fadd_rn(__fadd_rn(s01, s23), __fadd_rn(s45, s67));
}

__device__ __forceinline__ float sq_sum_numpy(const float* __restrict__ p) {
    float h0 = half_sq_sum(p);
    float h1 = half_sq_sum(p + 128);
    return __fadd_rn(h0, h1);
}

// ---------------- K0: codebook squared norms (fp32, numpy order) -----------
__global__ __launch_bounds__(256) void k_prepB(const float* __restrict__ E,
                                               float* __restrict__ B32) {
    int j = blockIdx.x * 256 + threadIdx.x;
    if (j >= KC) return;
    B32[j] = sq_sum_numpy(E + (size_t)j * DIM);
}

// ---------------- K1: fused dist + argmin + gather + loss ------------------
// block = 256 threads; tile 128 rows x 128 cols; D staged in chunks of 16.
// 32 KB LDS (double-buffered 2x16KB) + VGPR<=128 -> 4 blocks/CU (2x occupancy
// vs the 64KB/TD=32 version).  XOR-swizzled float4 chunks: chunk ^= (d>>2)<<1
// inside each unpadded 128-float row -> <=2-way (free) on both ds_write and
// ds_read_b128.  Staging is reg-staged issue-early / write-late, one barrier
// per staging.  acc[i][j] is a single fp32 fma chain over d = 0..255
// ascending from 0 -- bit-identical argmin to the passing kernel.
// Epilogue fuses the old k_out/k_idxout: gather E rows, write outputs,
// histogram atomics, fp64 loss block-reduce (+1 atomicAdd per block).
#define TM 128
#define TN 128
#define TD 16
#define BUFF 2048      // floats per staged array  (TD*128)
#define BSTR 4096      // floats per buffer slot   (Xs+Es)

__global__ __launch_bounds__(256, 4) void k_pass1(
    const float* __restrict__ X, const float* __restrict__ E,
    const float* __restrict__ B32, float* __restrict__ out0,
    float* __restrict__ out1, int* __restrict__ counts,
    double* __restrict__ lossacc)
{
    __shared__ __align__(16) float sm[2 * BSTR + 128];   // 33280 B
    float* asq = sm + 2 * BSTR;                          // row norms [128]

    const int tid = threadIdx.x;
    const int tx  = tid & 15;        // col group: cols {tx*4..+3, 64+tx*4..+3}
    const int ty  = tid >> 4;        // row group (8 rows each)
    const int rowbase = blockIdx.x * TM;

    float4 xv0, xv1, ev0, ev1;

#define LOADR(cbn, dcn)                                                         \
    do {                                                                        \
        int fi_, r_, d4_;                                                       \
        fi_ = tid;       r_ = fi_ >> 2; d4_ = (fi_ & 3) << 2;                   \
        xv0 = *(const float4*)(X + (size_t)(rowbase + r_) * DIM + (dcn) + d4_); \
        ev0 = *(const float4*)(E + (size_t)((cbn) + r_) * DIM + (dcn) + d4_);   \
        fi_ = tid + 256; r_ = fi_ >> 2; d4_ = (fi_ & 3) << 2;                   \
        xv1 = *(const float4*)(X + (size_t)(rowbase + r_) * DIM + (dcn) + d4_); \
        ev1 = *(const float4*)(E + (size_t)((cbn) + r_) * DIM + (dcn) + d4_);   \
    } while (0)

// element (d4+j, col r) -> offset (d4+j)*128 + (((r>>2) ^ ((d4>>2)<<1))<<2) + (r&3)
#define WRITE1(Xs_, Es_, v_, e_, fif_)                                          \
    do {                                                                        \
        int r_ = (fif_) >> 2, d4_ = ((fif_) & 3) << 2;                          \
        int off_ = d4_ * 128 + ((((r_) >> 2) ^ ((d4_ >> 2) << 1)) << 2) + ((r_) & 3); \
        (Xs_)[off_]       = v_.x; (Xs_)[off_ + 128] = v_.y;                     \
        (Xs_)[off_ + 256] = v_.z; (Xs_)[off_ + 384] = v_.w;                     \
        (Es_)[off_]       = e_.x; (Es_)[off_ + 128] = e_.y;                     \
        (Es_)[off_ + 256] = e_.z; (Es_)[off_ + 384] = e_.w;                     \
    } while (0)

#define WRITEB(b)                                                               \
    do {                                                                        \
        float* Xs_ = sm + (b) * BSTR;                                           \
        float* Es_ = Xs_ + BUFF;                                                \
        WRITE1(Xs_, Es_, xv0, ev0, tid);                                        \
        WRITE1(Xs_, Es_, xv1, ev1, tid + 256);                                  \
    } while (0)

    // ---- prologue: issue first staging loads early ----
    LOADR(0, 0);

    // ---- fused row-norm prep (2 threads per row, numpy halves) ----
    {
        int r = tid >> 1, h = tid & 1;
        sm[(r << 1) + h] = half_sq_sum(X + (size_t)(rowbase + r) * DIM + (h << 7));
    }
    __syncthreads();
    if (tid < TM) asq[tid] = __fadd_rn(sm[tid << 1], sm[(tid << 1) + 1]);
    __syncthreads();
    WRITEB(0);

    float v1[8]; int i1[8];
#pragma unroll
    for (int i = 0; i < 8; ++i) { v1[i] = 3.0e38f; i1[i] = 0; }

    int cur = 0;
    for (int cb8 = 0; cb8 < 8; ++cb8) {
        const int cbase = cb8 * TN;

        float acc[8][8];
#pragma unroll
        for (int i = 0; i < 8; ++i)
#pragma unroll
            for (int j = 0; j < 8; ++j) acc[i][j] = 0.0f;

        for (int dcc = 0; dcc < 16; ++dcc) {
            const int s = cb8 * 16 + dcc;
            __syncthreads();                 // buf[cur] staged & other buf free
            if (s < 127) {
                const int sn = s + 1;
                LOADR((sn >> 4) * TN, (sn & 15) * TD);
            }
            {
                const float* Xc = sm + cur * BSTR;
                const float* Ec = Xc + BUFF;
#pragma unroll 2
                for (int q = 0; q < 4; ++q) {
                    const int m = q << 1;
                    const float* xp0 = Xc + q * 512 + (((2 * ty)     ^ m) << 2);
                    const float* xp1 = Xc + q * 512 + (((2 * ty + 1) ^ m) << 2);
                    const float* ep0 = Ec + q * 512 + ((tx ^ m) << 2);
#pragma unroll
                    for (int di = 0; di < 4; ++di) {
                        float4 t0 = *(const float4*)(xp0 + di * 128);
                        float4 t1 = *(const float4*)(xp1 + di * 128);
                        float4 u0 = *(const float4*)(ep0 + di * 128);
                        float4 u1 = *(const float4*)(ep0 + di * 128 + 64);
                        float xr[8] = {t0.x, t0.y, t0.z, t0.w, t1.x, t1.y, t1.z, t1.w};
                        float er[8] = {u0.x, u0.y, u0.z, u0.w, u1.x, u1.y, u1.z, u1.w};
#pragma unroll
                        for (int i = 0; i < 8; ++i)
#pragma unroll
                            for (int j = 0; j < 8; ++j)
                                acc[i][j] = fmaf(xr[i], er[j], acc[i][j]);
                    }
                }
            }
            if (s < 127) WRITEB(cur ^ 1);    // write-late: lands in other buffer
            cur ^= 1;
        }

        // fold this col-block: dist = fl(fl(A + B) - 2*dot), numpy rounding.
        float4 bq0 = *(const float4*)(B32 + cbase + (tx << 2));
        float4 bq1 = *(const float4*)(B32 + cbase + 64 + (tx << 2));
        float bvv[8] = {bq0.x, bq0.y, bq0.z, bq0.w, bq1.x, bq1.y, bq1.z, bq1.w};
#pragma unroll
        for (int j = 0; j < 8; ++j) {
            const int c = cbase + ((j < 4) ? ((tx << 2) + j)
                                           : (64 + (tx << 2) + (j - 4)));
#pragma unroll
            for (int i = 0; i < 8; ++i) {
                float Cv  = __fmul_rn(2.0f, acc[i][j]);
                float t1v = __fadd_rn(asq[ty * 8 + i], bvv[j]);
                float dv  = __fsub_rn(t1v, Cv);
                // strict < keeps first (lowest) index; c ascends per thread
                if (dv < v1[i]) { v1[i] = dv; i1[i] = c; }
            }
        }
    }

    // ---- merge (val, idx) across the 16 col-group threads per row ----
    __syncthreads();
    float* Mv  = sm;                         // [128][16] floats
    int*   Mi  = (int*)(sm + 2048);          // [128][16] ints
    int*   sIdx = (int*)(sm + 4096);         // [128] final indices
#pragma unroll
    for (int i = 0; i < 8; ++i) {
        int r = ty * 8 + i;
        Mv[r * 16 + tx] = v1[i];
        Mi[r * 16 + tx] = i1[i];
    }
    __syncthreads();
    if (tid < TM) {
        int r = tid;
        float bv = Mv[r * 16];
        int   bi = Mi[r * 16];
        for (int t = 1; t < 16; ++t) {
            float av = Mv[r * 16 + t];
            int   ai = Mi[r * 16 + t];
            if (av < bv || (av == bv && ai < bi)) { bv = av; bi = ai; }
        }
        sIdx[r] = bi;
        out1[rowbase + r] = (float)bi;
        atomicAdd(&counts[bi], 1);
    }
    __syncthreads();

    // ---- fused gather + quantized output + fp64 loss ----
    const size_t base = (size_t)rowbase * DIM;
    double s = 0.0;
#pragma unroll 4
    for (int g = 0; g < 32; ++g) {
        int fi  = tid + g * 256;             // 0..8191
        int row = fi >> 6;
        int d4  = fi & 63;
        int j = sIdx[row];
        float4 q = *(const float4*)(E + (size_t)j * DIM + d4 * 4);
        float4 x = *(const float4*)(X + base + (size_t)fi * 4);
        *(float4*)(out0 + base + (size_t)fi * 4) = q;
        double dx;
        dx = (double)q.x - (double)x.x; s = fma(dx, dx, s);
        dx = (double)q.y - (double)x.y; s = fma(dx, dx, s);
        dx = (double)q.z - (double)x.z; s = fma(dx, dx, s);
        dx = (double)q.w - (double)x.w; s = fma(dx, dx, s);
    }
#pragma unroll
    for (int off = 32; off > 0; off >>= 1) s += __shfl_down(s, off, 64);
    double* wsum = (double*)(sm + 4352);     // 16B-aligned, clear of sIdx
    int lane = tid & 63, wv = tid >> 6;
    if (lane == 0) wsum[wv] = s;
    __syncthreads();
    if (tid == 0) {
        double t = wsum[0] + wsum[1] + wsum[2] + wsum[3];
        atomicAdd(lossacc, t);
    }
#undef LOADR
#undef WRITE1
#undef WRITEB
}

// ---------------- K4: perplexity + loss finalize ----------------
__global__ void k_fin(const int* __restrict__ counts,
                      const double* __restrict__ lossacc,
                      float* __restrict__ out_pl)
{
    __shared__ double sh[256];
    double s = 0.0;
    for (int i = threadIdx.x; i < KC; i += 256) {
        double p = (double)counts[i] / 65536.0;
        s += p * log(p + 1.1920928955078125e-07);   // EPS = fp32 eps exactly
    }
    sh[threadIdx.x] = s;
    __syncthreads();
    for (int off = 128; off > 0; off >>= 1) {
        if (threadIdx.x < off) sh[threadIdx.x] += sh[threadIdx.x + off];
        __syncthreads();
    }
    if (threadIdx.x == 0) {
        out_pl[0] = (float)exp(-sh[0]);
        out_pl[1] = (float)((*lossacc / (double)NQ) * 1.1);  // q + 0.1*e latent
    }
}

extern "C" void kernel_launch(void* const* d_in, const int* in_sizes, int n_in,
                              void* d_out, int out_size, void* d_ws, size_t ws_size,
                              hipStream_t stream) {
    const float* X = (const float*)d_in[0];
    const float* E = (const float*)d_in[1];
    float* out = (float*)d_out;
    char* ws = (char*)d_ws;

    double* lossacc = (double*)(ws + 0);
    int*    counts  = (int*)(ws + 16);
    float*  B32     = (float*)(ws + 4224);

    // zero lossacc + counts (B32 fully overwritten by k_prepB)
    hipMemsetAsync(d_ws, 0, 4224, stream);

    hipLaunchKernelGGL(k_prepB, dim3(4),         dim3(256), 0, stream, E, B32);
    hipLaunchKernelGGL(k_pass1, dim3(ROWS / TM), dim3(256), 0, stream,
                       X, E, B32, out, out + NQ, counts, lossacc);
    hipLaunchKernelGGL(k_fin,   dim3(1),         dim3(256), 0, stream,
                       counts, lossacc, out + NQ + 65536);
}

// Round 3
// 577.557 us; speedup vs baseline: 1.5663x; 1.5663x over previous
//
#include <hip/hip_runtime.h>
#include <math.h>

#define ROWS 65536
#define DIM  256
#define KC   1024
#define NQ   (ROWS * DIM)

// ---- ws layout (bytes) ----
// [0]      double lossacc
// [16]     int    counts[1024]        (ends 4112)
// [4224]   float  B32[1024]           (ends 8320)

// ---------------------------------------------------------------------------
// numpy pairwise sum-of-squares helpers (identical op order to the passing
// kernel: two 128-halves, 8 accumulators each, tree combine, halves added
// last; __fmul_rn/__fadd_rn forbid fma contraction).
// ---------------------------------------------------------------------------
__device__ __forceinline__ float half_sq_sum(const float* __restrict__ a) {
    float4 u0 = *(const float4*)(a);
    float4 u1 = *(const float4*)(a + 4);
    float r0 = __fmul_rn(u0.x, u0.x);
    float r1 = __fmul_rn(u0.y, u0.y);
    float r2 = __fmul_rn(u0.z, u0.z);
    float r3 = __fmul_rn(u0.w, u0.w);
    float r4 = __fmul_rn(u1.x, u1.x);
    float r5 = __fmul_rn(u1.y, u1.y);
    float r6 = __fmul_rn(u1.z, u1.z);
    float r7 = __fmul_rn(u1.w, u1.w);
    for (int i = 8; i < 128; i += 8) {
        float4 v0 = *(const float4*)(a + i);
        float4 v1 = *(const float4*)(a + i + 4);
        r0 = __fadd_rn(r0, __fmul_rn(v0.x, v0.x));
        r1 = __fadd_rn(r1, __fmul_rn(v0.y, v0.y));
        r2 = __fadd_rn(r2, __fmul_rn(v0.z, v0.z));
        r3 = __fadd_rn(r3, __fmul_rn(v0.w, v0.w));
        r4 = __fadd_rn(r4, __fmul_rn(v1.x, v1.x));
        r5 = __fadd_rn(r5, __fmul_rn(v1.y, v1.y));
        r6 = __fadd_rn(r6, __fmul_rn(v1.z, v1.z));
        r7 = __fadd_rn(r7, __fmul_rn(v1.w, v1.w));
    }
    float s01 = __fadd_rn(r0, r1);
    float s23 = __fadd_rn(r2, r3);
    float s45 = __fadd_rn(r4, r5);
    float s67 = __fadd_rn(r6, r7);
    return __fadd_rn(__fadd_rn(s01, s23), __fadd_rn(s45, s67));
}

__device__ __forceinline__ float sq_sum_numpy(const float* __restrict__ p) {
    float h0 = half_sq_sum(p);
    float h1 = half_sq_sum(p + 128);
    return __fadd_rn(h0, h1);
}

// ---------------- K0: codebook squared norms (fp32, numpy order) -----------
__global__ __launch_bounds__(256) void k_prepB(const float* __restrict__ E,
                                               float* __restrict__ B32) {
    int j = blockIdx.x * 256 + threadIdx.x;
    if (j >= KC) return;
    B32[j] = sq_sum_numpy(E + (size_t)j * DIM);
}

// ---------------- K1: fused dist + argmin + gather + loss ------------------
// block = 256 threads; tile 64 rows x 128 cols; D staged in chunks of 16.
// Grid = 1024 blocks = 4 blocks/CU (the R0-R2 grid of 512 capped occupancy
// at 2 blocks/CU regardless of resources).  LDS 24.8 KB double-buffered,
// VGPR target < 128 -> occupancy is grid-limited at 4 blocks/CU (16 waves).
// XOR-quad swizzle: element (d, c) -> d*W + (((c>>2) ^ (((d>>2)&1)<<2))<<2)
// + (c&3)  (W = 64 for Xs, 128 for Es) -> <=2-way (free) on ds_write and
// ds_read_b128; X-fragment reads are 16-lane broadcasts.
// acc[i][j] is a single fp32 fma chain over d = 0..255 ascending from 0 --
// bit-identical argmin to the passing kernel.  Epilogue fuses gather,
// outputs, histogram, fp64 loss (1 atomicAdd per block).
#define TM 64
#define TN 128
#define TD 16
#define XBUF 1024      // 16 d x 64 rows
#define EBUF 2048      // 16 d x 128 cols
#define BSTR 3072      // floats per buffer slot (Xs+Es)

__global__ __launch_bounds__(256, 2) void k_pass1(
    const float* __restrict__ X, const float* __restrict__ E,
    const float* __restrict__ B32, float* __restrict__ out0,
    float* __restrict__ out1, int* __restrict__ counts,
    double* __restrict__ lossacc)
{
    __shared__ __align__(16) float sm[2 * BSTR + 64];    // 24832 B
    float* asq = sm + 2 * BSTR;                          // row norms [64]

    const int tid = threadIdx.x;
    const int tx  = tid & 15;        // col group: cols {tx*4..+3, 64+tx*4..+3}
    const int ty  = tid >> 4;        // row group: rows ty*4..+3   (0..15)
    const int rowbase = blockIdx.x * TM;

    float4 xv0, ev0, ev1;

#define LOADR(cbn, dcn)                                                          \
    do {                                                                         \
        int r_ = tid >> 2, d4_ = (tid & 3) << 2;                                 \
        xv0 = *(const float4*)(X + (size_t)(rowbase + r_) * DIM + (dcn) + d4_);  \
        ev0 = *(const float4*)(E + (size_t)((cbn) + r_) * DIM + (dcn) + d4_);    \
        ev1 = *(const float4*)(E + (size_t)((cbn) + 64 + r_) * DIM + (dcn) + d4_);\
    } while (0)

// swizzled offset pieces: sx = ((d4>>2)&1)<<2 = (tid&1)<<2 (d4 = (tid&3)*4)
#define WRITEB(b)                                                                \
    do {                                                                         \
        float* Xs_ = sm + (b) * BSTR;                                            \
        float* Es_ = Xs_ + XBUF;                                                 \
        int r_ = tid >> 2, d4_ = (tid & 3) << 2;                                 \
        int sx_ = (tid & 1) << 2;                                                \
        int o_  = (((r_ >> 2) ^ sx_) << 2) + (r_ & 3);                           \
        Xs_[(d4_ + 0) * 64 + o_] = xv0.x;                                        \
        Xs_[(d4_ + 1) * 64 + o_] = xv0.y;                                        \
        Xs_[(d4_ + 2) * 64 + o_] = xv0.z;                                        \
        Xs_[(d4_ + 3) * 64 + o_] = xv0.w;                                        \
        Es_[(d4_ + 0) * 128 + o_] = ev0.x;                                       \
        Es_[(d4_ + 1) * 128 + o_] = ev0.y;                                       \
        Es_[(d4_ + 2) * 128 + o_] = ev0.z;                                       \
        Es_[(d4_ + 3) * 128 + o_] = ev0.w;                                       \
        Es_[(d4_ + 0) * 128 + 64 + o_] = ev1.x;                                  \
        Es_[(d4_ + 1) * 128 + 64 + o_] = ev1.y;                                  \
        Es_[(d4_ + 2) * 128 + 64 + o_] = ev1.z;                                  \
        Es_[(d4_ + 3) * 128 + 64 + o_] = ev1.w;                                  \
    } while (0)

    // ---- prologue: issue first staging loads early ----
    LOADR(0, 0);

    // ---- fused row-norm prep (2 threads per row, numpy halves) ----
    if (tid < 128) {
        int r = tid >> 1, h = tid & 1;
        sm[(r << 1) + h] = half_sq_sum(X + (size_t)(rowbase + r) * DIM + (h << 7));
    }
    __syncthreads();
    if (tid < TM) asq[tid] = __fadd_rn(sm[tid << 1], sm[(tid << 1) + 1]);
    __syncthreads();
    WRITEB(0);

    float v1[4]; int i1[4];
#pragma unroll
    for (int i = 0; i < 4; ++i) { v1[i] = 3.0e38f; i1[i] = 0; }

    int cur = 0;
    for (int cb8 = 0; cb8 < 8; ++cb8) {
        const int cbase = cb8 * TN;

        float acc[4][8];
#pragma unroll
        for (int i = 0; i < 4; ++i)
#pragma unroll
            for (int j = 0; j < 8; ++j) acc[i][j] = 0.0f;

        for (int dcc = 0; dcc < 16; ++dcc) {
            const int s = (cb8 << 4) + dcc;
            __syncthreads();                 // buf[cur] staged & other buf free
            if (s < 127) {
                const int sn = s + 1;
                LOADR((sn >> 4) * TN, (sn & 15) * TD);
            }
            {
                const float* Xc = sm + cur * BSTR;
                const float* Ec = Xc + XBUF;
#pragma unroll 2
                for (int q = 0; q < 4; ++q) {
                    const int sq = (q & 1) << 2;
                    const float* xb = Xc + (q << 8) + (((ty ^ sq) & 15) << 2);
                    const float* eb = Ec + (q << 9) + ((tx ^ sq) << 2);
#pragma unroll
                    for (int dj = 0; dj < 4; ++dj) {
                        float4 t0 = *(const float4*)(xb + dj * 64);
                        float4 u0 = *(const float4*)(eb + dj * 128);
                        float4 u1 = *(const float4*)(eb + dj * 128 + 64);
                        float xr[4] = {t0.x, t0.y, t0.z, t0.w};
                        float er[8] = {u0.x, u0.y, u0.z, u0.w, u1.x, u1.y, u1.z, u1.w};
#pragma unroll
                        for (int i = 0; i < 4; ++i)
#pragma unroll
                            for (int j = 0; j < 8; ++j)
                                acc[i][j] = fmaf(xr[i], er[j], acc[i][j]);
                    }
                }
            }
            if (s < 127) WRITEB(cur ^ 1);    // write-late: lands in other buffer
            cur ^= 1;
        }

        // fold this col-block: dist = fl(fl(A + B) - 2*dot), numpy rounding.
        float4 bq0 = *(const float4*)(B32 + cbase + (tx << 2));
        float4 bq1 = *(const float4*)(B32 + cbase + 64 + (tx << 2));
        float bvv[8] = {bq0.x, bq0.y, bq0.z, bq0.w, bq1.x, bq1.y, bq1.z, bq1.w};
#pragma unroll
        for (int j = 0; j < 8; ++j) {
            const int c = cbase + ((j < 4) ? ((tx << 2) + j)
                                           : (64 + (tx << 2) + (j - 4)));
#pragma unroll
            for (int i = 0; i < 4; ++i) {
                float Cv  = __fmul_rn(2.0f, acc[i][j]);
                float t1v = __fadd_rn(asq[(ty << 2) + i], bvv[j]);
                float dv  = __fsub_rn(t1v, Cv);
                // strict < keeps first (lowest) index; c ascends per thread
                if (dv < v1[i]) { v1[i] = dv; i1[i] = c; }
            }
        }
    }

    // ---- merge (val, idx) across the 16 col-group threads per row ----
    __syncthreads();
    float* Mv   = sm;                        // [64][16] floats
    int*   Mi   = (int*)(sm + 1024);         // [64][16] ints
    int*   sIdx = (int*)(sm + 2048);         // [64] final indices
    double* wsum = (double*)(sm + 2112);     // [4] doubles (byte 8448, 8-aligned)
#pragma unroll
    for (int i = 0; i < 4; ++i) {
        int r = (ty << 2) + i;
        Mv[r * 16 + tx] = v1[i];
        Mi[r * 16 + tx] = i1[i];
    }
    __syncthreads();
    if (tid < TM) {
        int r = tid;
        float bv = Mv[r * 16];
        int   bi = Mi[r * 16];
        for (int t = 1; t < 16; ++t) {
            float av = Mv[r * 16 + t];
            int   ai = Mi[r * 16 + t];
            if (av < bv || (av == bv && ai < bi)) { bv = av; bi = ai; }
        }
        sIdx[r] = bi;
        out1[rowbase + r] = (float)bi;
        atomicAdd(&counts[bi], 1);
    }
    __syncthreads();

    // ---- fused gather + quantized output + fp64 loss ----
    const size_t base = (size_t)rowbase * DIM;
    double s = 0.0;
#pragma unroll 4
    for (int g = 0; g < 16; ++g) {
        int fi  = tid + g * 256;             // 0..4095
        int row = fi >> 6;
        int d4  = fi & 63;
        int j = sIdx[row];
        float4 q = *(const float4*)(E + (size_t)j * DIM + d4 * 4);
        float4 x = *(const float4*)(X + base + (size_t)fi * 4);
        *(float4*)(out0 + base + (size_t)fi * 4) = q;
        double dx;
        dx = (double)q.x - (double)x.x; s = fma(dx, dx, s);
        dx = (double)q.y - (double)x.y; s = fma(dx, dx, s);
        dx = (double)q.z - (double)x.z; s = fma(dx, dx, s);
        dx = (double)q.w - (double)x.w; s = fma(dx, dx, s);
    }
#pragma unroll
    for (int off = 32; off > 0; off >>= 1) s += __shfl_down(s, off, 64);
    int lane = tid & 63, wv = tid >> 6;
    if (lane == 0) wsum[wv] = s;
    __syncthreads();
    if (tid == 0) {
        double t = wsum[0] + wsum[1] + wsum[2] + wsum[3];
        atomicAdd(lossacc, t);
    }
#undef LOADR
#undef WRITEB
}

// ---------------- K4: perplexity + loss finalize ----------------
__global__ void k_fin(const int* __restrict__ counts,
                      const double* __restrict__ lossacc,
                      float* __restrict__ out_pl)
{
    __shared__ double sh[256];
    double s = 0.0;
    for (int i = threadIdx.x; i < KC; i += 256) {
        double p = (double)counts[i] / 65536.0;
        s += p * log(p + 1.1920928955078125e-07);   // EPS = fp32 eps exactly
    }
    sh[threadIdx.x] = s;
    __syncthreads();
    for (int off = 128; off > 0; off >>= 1) {
        if (threadIdx.x < off) sh[threadIdx.x] += sh[threadIdx.x + off];
        __syncthreads();
    }
    if (threadIdx.x == 0) {
        out_pl[0] = (float)exp(-sh[0]);
        out_pl[1] = (float)((*lossacc / (double)NQ) * 1.1);  // q + 0.1*e latent
    }
}

extern "C" void kernel_launch(void* const* d_in, const int* in_sizes, int n_in,
                              void* d_out, int out_size, void* d_ws, size_t ws_size,
                              hipStream_t stream) {
    const float* X = (const float*)d_in[0];
    const float* E = (const float*)d_in[1];
    float* out = (float*)d_out;
    char* ws = (char*)d_ws;

    double* lossacc = (double*)(ws + 0);
    int*    counts  = (int*)(ws + 16);
    float*  B32     = (float*)(ws + 4224);

    // zero lossacc + counts (B32 fully overwritten by k_prepB)
    hipMemsetAsync(d_ws, 0, 4224, stream);

    hipLaunchKernelGGL(k_prepB, dim3(4),         dim3(256), 0, stream, E, B32);
    hipLaunchKernelGGL(k_pass1, dim3(ROWS / TM), dim3(256), 0, stream,
                       X, E, B32, out, out + NQ, counts, lossacc);
    hipLaunchKernelGGL(k_fin,   dim3(1),         dim3(256), 0, stream,
                       counts, lossacc, out + NQ + 65536);
}

// Round 4
// 531.977 us; speedup vs baseline: 1.7005x; 1.0857x over previous
//
#include <hip/hip_runtime.h>
#include <math.h>

#define ROWS 65536
#define DIM  256
#define KC   1024
#define NQ   (ROWS * DIM)

typedef float f2 __attribute__((ext_vector_type(2)));

// ---- ws layout (bytes) ----
// [0]      double lossacc
// [16]     int    counts[1024]        (ends 4112)
// [4224]   float  B32[1024]           (ends 8320)

// ---------------------------------------------------------------------------
// numpy pairwise sum-of-squares helpers (identical op order to the passing
// kernel: two 128-halves, 8 accumulators each, tree combine, halves added
// last; __fmul_rn/__fadd_rn forbid fma contraction).
// ---------------------------------------------------------------------------
__device__ __forceinline__ float half_sq_sum(const float* __restrict__ a) {
    float4 u0 = *(const float4*)(a);
    float4 u1 = *(const float4*)(a + 4);
    float r0 = __fmul_rn(u0.x, u0.x);
    float r1 = __fmul_rn(u0.y, u0.y);
    float r2 = __fmul_rn(u0.z, u0.z);
    float r3 = __fmul_rn(u0.w, u0.w);
    float r4 = __fmul_rn(u1.x, u1.x);
    float r5 = __fmul_rn(u1.y, u1.y);
    float r6 = __fmul_rn(u1.z, u1.z);
    float r7 = __fmul_rn(u1.w, u1.w);
    for (int i = 8; i < 128; i += 8) {
        float4 v0 = *(const float4*)(a + i);
        float4 v1 = *(const float4*)(a + i + 4);
        r0 = __fadd_rn(r0, __fmul_rn(v0.x, v0.x));
        r1 = __fadd_rn(r1, __fmul_rn(v0.y, v0.y));
        r2 = __fadd_rn(r2, __fmul_rn(v0.z, v0.z));
        r3 = __fadd_rn(r3, __fmul_rn(v0.w, v0.w));
        r4 = __fadd_rn(r4, __fmul_rn(v1.x, v1.x));
        r5 = __fadd_rn(r5, __fmul_rn(v1.y, v1.y));
        r6 = __fadd_rn(r6, __fmul_rn(v1.z, v1.z));
        r7 = __fadd_rn(r7, __fmul_rn(v1.w, v1.w));
    }
    float s01 = __fadd_rn(r0, r1);
    float s23 = __fadd_rn(r2, r3);
    float s45 = __fadd_rn(r4, r5);
    float s67 = __fadd_rn(r6, r7);
    return __fadd_rn(__fadd_rn(s01, s23), __fadd_rn(s45, s67));
}

__device__ __forceinline__ float sq_sum_numpy(const float* __restrict__ p) {
    float h0 = half_sq_sum(p);
    float h1 = half_sq_sum(p + 128);
    return __fadd_rn(h0, h1);
}

// ---------------- K0: codebook squared norms (fp32, numpy order) -----------
__global__ __launch_bounds__(256) void k_prepB(const float* __restrict__ E,
                                               float* __restrict__ B32) {
    int j = blockIdx.x * 256 + threadIdx.x;
    if (j >= KC) return;
    B32[j] = sq_sum_numpy(E + (size_t)j * DIM);
}

// ---------------- K1: fused dist + argmin + gather + loss ------------------
// R1 geometry (the measured-best compute structure): block = 256 threads,
// tile 128 rows x 128 cols, D staged in chunks of 32, 64 KB double-buffered
// XOR-swizzled LDS, grid 512 (2 blocks/CU).
// NEW: inner product uses PACKED fp32 fma (v_pk_fma_f32 via
// __builtin_elementwise_fma on float2 ext-vectors).  Each packed lane is
// exactly one scalar fmaf in the same d = 0..255 ascending chain ->
// bit-identical distances and argmin.  E-operand float2 pairs are free
// (consecutive VGPRs from ds_read_b128); X is splatted per row.
// Epilogue fuses gather, quantized output, index output, histogram, and the
// fp64 loss block-reduce (1 atomicAdd per block).
#define TM 128
#define TN 128
#define TD 32
#define BUFF 4096      // floats per staged array  (TD*128)
#define BSTR 8192      // floats per buffer slot   (Xs+Es)

__global__ __launch_bounds__(256, 2) void k_pass1(
    const float* __restrict__ X, const float* __restrict__ E,
    const float* __restrict__ B32, float* __restrict__ out0,
    float* __restrict__ out1, int* __restrict__ counts,
    double* __restrict__ lossacc)
{
    __shared__ __align__(16) float sm[2 * BSTR];   // 65536 B -> 2 blocks/CU

    const int tid = threadIdx.x;
    const int tx  = tid & 15;        // col group: cols {tx*4..+3, 64+tx*4..+3}
    const int ty  = tid >> 4;        // row group (8 rows each)
    const int rowbase = blockIdx.x * TM;

    float4 xv0, xv1, xv2, xv3, ev0, ev1, ev2, ev3;

#define LOADR(cbn, dcn)                                                         \
    do {                                                                        \
        int fi_, r_, d4_;                                                       \
        fi_ = tid;       r_ = fi_ >> 3; d4_ = (fi_ & 7) << 2;                   \
        xv0 = *(const float4*)(X + (size_t)(rowbase + r_) * DIM + (dcn) + d4_); \
        ev0 = *(const float4*)(E + (size_t)((cbn) + r_) * DIM + (dcn) + d4_);   \
        fi_ = tid + 256; r_ = fi_ >> 3; d4_ = (fi_ & 7) << 2;                   \
        xv1 = *(const float4*)(X + (size_t)(rowbase + r_) * DIM + (dcn) + d4_); \
        ev1 = *(const float4*)(E + (size_t)((cbn) + r_) * DIM + (dcn) + d4_);   \
        fi_ = tid + 512; r_ = fi_ >> 3; d4_ = (fi_ & 7) << 2;                   \
        xv2 = *(const float4*)(X + (size_t)(rowbase + r_) * DIM + (dcn) + d4_); \
        ev2 = *(const float4*)(E + (size_t)((cbn) + r_) * DIM + (dcn) + d4_);   \
        fi_ = tid + 768; r_ = fi_ >> 3; d4_ = (fi_ & 7) << 2;                   \
        xv3 = *(const float4*)(X + (size_t)(rowbase + r_) * DIM + (dcn) + d4_); \
        ev3 = *(const float4*)(E + (size_t)((cbn) + r_) * DIM + (dcn) + d4_);   \
    } while (0)

// element (row d4+j, col r) -> offset (d4+j)*128 + (((r>>2) ^ (d4>>2))<<2) + (r&3)
#define WRITE1(Xs_, Es_, v_, e_, fif_)                                          \
    do {                                                                        \
        int r_ = (fif_) >> 3, d4_ = ((fif_) & 7) << 2;                          \
        int off_ = d4_ * 128 + ((((r_) >> 2) ^ (d4_ >> 2)) << 2) + ((r_) & 3);  \
        (Xs_)[off_]       = v_.x; (Xs_)[off_ + 128] = v_.y;                     \
        (Xs_)[off_ + 256] = v_.z; (Xs_)[off_ + 384] = v_.w;                     \
        (Es_)[off_]       = e_.x; (Es_)[off_ + 128] = e_.y;                     \
        (Es_)[off_ + 256] = e_.z; (Es_)[off_ + 384] = e_.w;                     \
    } while (0)

#define WRITEB(b)                                                               \
    do {                                                                        \
        float* Xs_ = sm + (b) * BSTR;                                           \
        float* Es_ = Xs_ + BUFF;                                                \
        WRITE1(Xs_, Es_, xv0, ev0, tid);                                        \
        WRITE1(Xs_, Es_, xv1, ev1, tid + 256);                                  \
        WRITE1(Xs_, Es_, xv2, ev2, tid + 512);                                  \
        WRITE1(Xs_, Es_, xv3, ev3, tid + 768);                                  \
    } while (0)

    // ---- prologue: issue first staging loads early ----
    LOADR(0, 0);

    // ---- fused row-norm prep (2 threads per row, numpy halves) ----
    {
        int r = tid >> 1, h = tid & 1;
        sm[(r << 1) + h] = half_sq_sum(X + (size_t)(rowbase + r) * DIM + (h << 7));
    }
    __syncthreads();
    float a8[8];
#pragma unroll
    for (int i = 0; i < 8; ++i)
        a8[i] = __fadd_rn(sm[(ty * 8 + i) * 2], sm[(ty * 8 + i) * 2 + 1]);
    __syncthreads();
    WRITEB(0);

    float v1[8]; int i1[8];
#pragma unroll
    for (int i = 0; i < 8; ++i) { v1[i] = 3.0e38f; i1[i] = 0; }

    int cur = 0;
    for (int cb8 = 0; cb8 < 8; ++cb8) {
        const int cbase = cb8 * TN;

        f2 acc[8][4];
#pragma unroll
        for (int i = 0; i < 8; ++i)
#pragma unroll
            for (int j = 0; j < 4; ++j) acc[i][j] = (f2){0.0f, 0.0f};

        for (int dc8 = 0; dc8 < 8; ++dc8) {
            const int s = cb8 * 8 + dc8;
            __syncthreads();                 // buf[cur] staged & other buf free
            if (s < 63) {
                const int sn = s + 1;
                LOADR((sn >> 3) * TN, (sn & 7) * TD);
            }
            {
                const float* Xc = sm + cur * BSTR;
                const float* Ec = Xc + BUFF;
#pragma unroll 2
                for (int dq = 0; dq < 8; ++dq) {
                    const float* xp0 = Xc + dq * 512 + ((((ty << 1)    ) ^ dq) << 2);
                    const float* xp1 = Xc + dq * 512 + ((((ty << 1) | 1) ^ dq) << 2);
                    const float* ep0 = Ec + dq * 512 + ((tx ^ dq) << 2);
#pragma unroll
                    for (int ddi = 0; ddi < 4; ++ddi) {
                        float4 t0 = *(const float4*)(xp0 + ddi * 128);
                        float4 t1 = *(const float4*)(xp1 + ddi * 128);
                        float4 u0 = *(const float4*)(ep0 + ddi * 128);
                        float4 u1 = *(const float4*)(ep0 + ddi * 128 + 64);
                        f2 e0 = {u0.x, u0.y};
                        f2 e1 = {u0.z, u0.w};
                        f2 e2 = {u1.x, u1.y};
                        f2 e3 = {u1.z, u1.w};
#define ROWF(i_, xs_)                                                           \
                        {                                                       \
                            f2 xp_ = {xs_, xs_};                                \
                            acc[i_][0] = __builtin_elementwise_fma(xp_, e0, acc[i_][0]); \
                            acc[i_][1] = __builtin_elementwise_fma(xp_, e1, acc[i_][1]); \
                            acc[i_][2] = __builtin_elementwise_fma(xp_, e2, acc[i_][2]); \
                            acc[i_][3] = __builtin_elementwise_fma(xp_, e3, acc[i_][3]); \
                        }
                        ROWF(0, t0.x) ROWF(1, t0.y) ROWF(2, t0.z) ROWF(3, t0.w)
                        ROWF(4, t1.x) ROWF(5, t1.y) ROWF(6, t1.z) ROWF(7, t1.w)
#undef ROWF
                    }
                }
            }
            if (s < 63) WRITEB(cur ^ 1);     // write-late: lands in other buffer
            cur ^= 1;
        }

        // fold this col-block: dist = fl(fl(A + B) - 2*dot), numpy rounding.
        float4 bq0 = *(const float4*)(B32 + cbase + (tx << 2));
        float4 bq1 = *(const float4*)(B32 + cbase + 64 + (tx << 2));
        float bvv[8] = {bq0.x, bq0.y, bq0.z, bq0.w, bq1.x, bq1.y, bq1.z, bq1.w};
#pragma unroll
        for (int j = 0; j < 8; ++j) {
            const int c = cbase + ((j < 4) ? ((tx << 2) + j)
                                           : (64 + (tx << 2) + (j - 4)));
#pragma unroll
            for (int i = 0; i < 8; ++i) {
                float av  = acc[i][j >> 1][j & 1];
                float Cv  = __fmul_rn(2.0f, av);
                float t1v = __fadd_rn(a8[i], bvv[j]);
                float dv  = __fsub_rn(t1v, Cv);
                // strict < keeps first (lowest) index; c ascends per thread
                if (dv < v1[i]) { v1[i] = dv; i1[i] = c; }
            }
        }
    }

    // ---- merge (val, idx) across the 16 col-group threads per row ----
    __syncthreads();
    float* Mv   = sm;                        // [128][16] floats  (bytes 0..8191)
    int*   Mi   = (int*)(sm + 2048);         // [128][16] ints    (8192..16383)
    int*   sIdx = (int*)(sm + 4096);         // [128] final idx   (16384..16895)
    double* wsum = (double*)(sm + 4224);     // [4] doubles       (16896..16927)
#pragma unroll
    for (int i = 0; i < 8; ++i) {
        int r = ty * 8 + i;
        Mv[r * 16 + tx] = v1[i];
        Mi[r * 16 + tx] = i1[i];
    }
    __syncthreads();
    if (tid < TM) {
        int r = tid;
        float bv = Mv[r * 16];
        int   bi = Mi[r * 16];
        for (int t = 1; t < 16; ++t) {
            float av = Mv[r * 16 + t];
            int   ai = Mi[r * 16 + t];
            if (av < bv || (av == bv && ai < bi)) { bv = av; bi = ai; }
        }
        sIdx[r] = bi;
        out1[rowbase + r] = (float)bi;
        atomicAdd(&counts[bi], 1);
    }
    __syncthreads();

    // ---- fused gather + quantized output + fp64 loss ----
    const size_t base = (size_t)rowbase * DIM;
    double s = 0.0;
#pragma unroll 4
    for (int g = 0; g < 32; ++g) {
        int fi  = tid + g * 256;             // 0..8191
        int row = fi >> 6;
        int d4  = fi & 63;
        int j = sIdx[row];
        float4 q = *(const float4*)(E + (size_t)j * DIM + d4 * 4);
        float4 x = *(const float4*)(X + base + (size_t)fi * 4);
        *(float4*)(out0 + base + (size_t)fi * 4) = q;
        double dx;
        dx = (double)q.x - (double)x.x; s = fma(dx, dx, s);
        dx = (double)q.y - (double)x.y; s = fma(dx, dx, s);
        dx = (double)q.z - (double)x.z; s = fma(dx, dx, s);
        dx = (double)q.w - (double)x.w; s = fma(dx, dx, s);
    }
#pragma unroll
    for (int off = 32; off > 0; off >>= 1) s += __shfl_down(s, off, 64);
    int lane = tid & 63, wv = tid >> 6;
    if (lane == 0) wsum[wv] = s;
    __syncthreads();
    if (tid == 0) {
        double t = wsum[0] + wsum[1] + wsum[2] + wsum[3];
        atomicAdd(lossacc, t);
    }
#undef LOADR
#undef WRITE1
#undef WRITEB
}

// ---------------- K4: perplexity + loss finalize ----------------
__global__ void k_fin(const int* __restrict__ counts,
                      const double* __restrict__ lossacc,
                      float* __restrict__ out_pl)
{
    __shared__ double sh[256];
    double s = 0.0;
    for (int i = threadIdx.x; i < KC; i += 256) {
        double p = (double)counts[i] / 65536.0;
        s += p * log(p + 1.1920928955078125e-07);   // EPS = fp32 eps exactly
    }
    sh[threadIdx.x] = s;
    __syncthreads();
    for (int off = 128; off > 0; off >>= 1) {
        if (threadIdx.x < off) sh[threadIdx.x] += sh[threadIdx.x + off];
        __syncthreads();
    }
    if (threadIdx.x == 0) {
        out_pl[0] = (float)exp(-sh[0]);
        out_pl[1] = (float)((*lossacc / (double)NQ) * 1.1);  // q + 0.1*e latent
    }
}

extern "C" void kernel_launch(void* const* d_in, const int* in_sizes, int n_in,
                              void* d_out, int out_size, void* d_ws, size_t ws_size,
                              hipStream_t stream) {
    const float* X = (const float*)d_in[0];
    const float* E = (const float*)d_in[1];
    float* out = (float*)d_out;
    char* ws = (char*)d_ws;

    double* lossacc = (double*)(ws + 0);
    int*    counts  = (int*)(ws + 16);
    float*  B32     = (float*)(ws + 4224);

    // zero lossacc + counts (B32 fully overwritten by k_prepB)
    hipMemsetAsync(d_ws, 0, 4224, stream);

    hipLaunchKernelGGL(k_prepB, dim3(4),         dim3(256), 0, stream, E, B32);
    hipLaunchKernelGGL(k_pass1, dim3(ROWS / TM), dim3(256), 0, stream,
                       X, E, B32, out, out + NQ, counts, lossacc);
    hipLaunchKernelGGL(k_fin,   dim3(1),         dim3(256), 0, stream,
                       counts, lossacc, out + NQ + 65536);
}

// Round 5
// 518.041 us; speedup vs baseline: 1.7463x; 1.0269x over previous
//
#include <hip/hip_runtime.h>
#include <math.h>

#define ROWS 65536
#define DIM  256
#define KC   1024
#define NQ   (ROWS * DIM)

typedef float f2 __attribute__((ext_vector_type(2)));
typedef float f4v __attribute__((ext_vector_type(4)));

// ---- ws layout (bytes) ----
// [0]      double lossacc
// [16]     int    counts[1024]        (ends 4112)
// [4224]   float  B32[1024]           (ends 8320)

// ---------------------------------------------------------------------------
// numpy pairwise sum-of-squares helpers (identical op order to the passing
// kernel: two 128-halves, 8 accumulators each, tree combine, halves added
// last; __fmul_rn/__fadd_rn forbid fma contraction).
// ---------------------------------------------------------------------------
__device__ __forceinline__ float half_sq_sum(const float* __restrict__ a) {
    float4 u0 = *(const float4*)(a);
    float4 u1 = *(const float4*)(a + 4);
    float r0 = __fmul_rn(u0.x, u0.x);
    float r1 = __fmul_rn(u0.y, u0.y);
    float r2 = __fmul_rn(u0.z, u0.z);
    float r3 = __fmul_rn(u0.w, u0.w);
    float r4 = __fmul_rn(u1.x, u1.x);
    float r5 = __fmul_rn(u1.y, u1.y);
    float r6 = __fmul_rn(u1.z, u1.z);
    float r7 = __fmul_rn(u1.w, u1.w);
    for (int i = 8; i < 128; i += 8) {
        float4 v0 = *(const float4*)(a + i);
        float4 v1 = *(const float4*)(a + i + 4);
        r0 = __fadd_rn(r0, __fmul_rn(v0.x, v0.x));
        r1 = __fadd_rn(r1, __fmul_rn(v0.y, v0.y));
        r2 = __fadd_rn(r2, __fmul_rn(v0.z, v0.z));
        r3 = __fadd_rn(r3, __fmul_rn(v0.w, v0.w));
        r4 = __fadd_rn(r4, __fmul_rn(v1.x, v1.x));
        r5 = __fadd_rn(r5, __fmul_rn(v1.y, v1.y));
        r6 = __fadd_rn(r6, __fmul_rn(v1.z, v1.z));
        r7 = __fadd_rn(r7, __fmul_rn(v1.w, v1.w));
    }
    float s01 = __fadd_rn(r0, r1);
    float s23 = __fadd_rn(r2, r3);
    float s45 = __fadd_rn(r4, r5);
    float s67 = __fadd_rn(r6, r7);
    return __fadd_rn(__fadd_rn(s01, s23), __fadd_rn(s45, s67));
}

__device__ __forceinline__ float sq_sum_numpy(const float* __restrict__ p) {
    float h0 = half_sq_sum(p);
    float h1 = half_sq_sum(p + 128);
    return __fadd_rn(h0, h1);
}

// ---------------- K0: codebook squared norms (fp32, numpy order) -----------
__global__ __launch_bounds__(256) void k_prepB(const float* __restrict__ E,
                                               float* __restrict__ B32) {
    int j = blockIdx.x * 256 + threadIdx.x;
    if (j >= KC) return;
    B32[j] = sq_sum_numpy(E + (size_t)j * DIM);
}

// ---------------- K1: fused dist + argmin + gather + loss ------------------
// R1/R4 geometry: block = 256 threads, tile 128 rows x 128 cols, D staged in
// chunks of 32, 64 KB double-buffered XOR-swizzled LDS, grid 512.
// NEW: inner product via v_pk_fma_f32 (VOP3P, inline asm) -- 2 independent
// fp32 FMAs per instruction.  X-row pairs come straight from ds_read_b128;
// op_sel/op_sel_hi broadcasts the lo/hi word of the X pair, so no splat
// movs.  Each packed lane is exactly one fmaf in the same d = 0..255
// ascending chain -> bit-identical distances and argmin.
// Epilogue fuses gather, quantized output, index output, histogram, and the
// fp64 loss block-reduce (1 atomicAdd per block).
#define TM 128
#define TN 128
#define TD 32
#define BUFF 4096      // floats per staged array  (TD*128)
#define BSTR 8192      // floats per buffer slot   (Xs+Es)

// d = pk_fma(x.broadcast_lo, e, d):  both halves use x.word0
#define PKL(d_, x_, e_)                                                         \
    asm("v_pk_fma_f32 %0, %1, %2, %0 op_sel:[0,0,0] op_sel_hi:[0,1,1]"          \
        : "+v"(d_) : "v"(x_), "v"(e_));
// d = pk_fma(x.broadcast_hi, e, d):  both halves use x.word1
#define PKH(d_, x_, e_)                                                         \
    asm("v_pk_fma_f32 %0, %1, %2, %0 op_sel:[1,0,0] op_sel_hi:[1,1,1]"          \
        : "+v"(d_) : "v"(x_), "v"(e_));

__global__ __launch_bounds__(256, 2) void k_pass1(
    const float* __restrict__ X, const float* __restrict__ E,
    const float* __restrict__ B32, float* __restrict__ out0,
    float* __restrict__ out1, int* __restrict__ counts,
    double* __restrict__ lossacc)
{
    __shared__ __align__(16) float sm[2 * BSTR];   // 65536 B -> 2 blocks/CU

    const int tid = threadIdx.x;
    const int tx  = tid & 15;        // col group: cols {tx*4..+3, 64+tx*4..+3}
    const int ty  = tid >> 4;        // row group (8 rows each)
    const int rowbase = blockIdx.x * TM;

    float4 xv0, xv1, xv2, xv3, ev0, ev1, ev2, ev3;

#define LOADR(cbn, dcn)                                                         \
    do {                                                                        \
        int fi_, r_, d4_;                                                       \
        fi_ = tid;       r_ = fi_ >> 3; d4_ = (fi_ & 7) << 2;                   \
        xv0 = *(const float4*)(X + (size_t)(rowbase + r_) * DIM + (dcn) + d4_); \
        ev0 = *(const float4*)(E + (size_t)((cbn) + r_) * DIM + (dcn) + d4_);   \
        fi_ = tid + 256; r_ = fi_ >> 3; d4_ = (fi_ & 7) << 2;                   \
        xv1 = *(const float4*)(X + (size_t)(rowbase + r_) * DIM + (dcn) + d4_); \
        ev1 = *(const float4*)(E + (size_t)((cbn) + r_) * DIM + (dcn) + d4_);   \
        fi_ = tid + 512; r_ = fi_ >> 3; d4_ = (fi_ & 7) << 2;                   \
        xv2 = *(const float4*)(X + (size_t)(rowbase + r_) * DIM + (dcn) + d4_); \
        ev2 = *(const float4*)(E + (size_t)((cbn) + r_) * DIM + (dcn) + d4_);   \
        fi_ = tid + 768; r_ = fi_ >> 3; d4_ = (fi_ & 7) << 2;                   \
        xv3 = *(const float4*)(X + (size_t)(rowbase + r_) * DIM + (dcn) + d4_); \
        ev3 = *(const float4*)(E + (size_t)((cbn) + r_) * DIM + (dcn) + d4_);   \
    } while (0)

// element (row d4+j, col r) -> offset (d4+j)*128 + (((r>>2) ^ (d4>>2))<<2) + (r&3)
#define WRITE1(Xs_, Es_, v_, e_, fif_)                                          \
    do {                                                                        \
        int r_ = (fif_) >> 3, d4_ = ((fif_) & 7) << 2;                          \
        int off_ = d4_ * 128 + ((((r_) >> 2) ^ (d4_ >> 2)) << 2) + ((r_) & 3);  \
        (Xs_)[off_]       = v_.x; (Xs_)[off_ + 128] = v_.y;                     \
        (Xs_)[off_ + 256] = v_.z; (Xs_)[off_ + 384] = v_.w;                     \
        (Es_)[off_]       = e_.x; (Es_)[off_ + 128] = e_.y;                     \
        (Es_)[off_ + 256] = e_.z; (Es_)[off_ + 384] = e_.w;                     \
    } while (0)

#define WRITEB(b)                                                               \
    do {                                                                        \
        float* Xs_ = sm + (b) * BSTR;                                           \
        float* Es_ = Xs_ + BUFF;                                                \
        WRITE1(Xs_, Es_, xv0, ev0, tid);                                        \
        WRITE1(Xs_, Es_, xv1, ev1, tid + 256);                                  \
        WRITE1(Xs_, Es_, xv2, ev2, tid + 512);                                  \
        WRITE1(Xs_, Es_, xv3, ev3, tid + 768);                                  \
    } while (0)

    // ---- prologue: issue first staging loads early ----
    LOADR(0, 0);

    // ---- fused row-norm prep (2 threads per row, numpy halves) ----
    {
        int r = tid >> 1, h = tid & 1;
        sm[(r << 1) + h] = half_sq_sum(X + (size_t)(rowbase + r) * DIM + (h << 7));
    }
    __syncthreads();
    float a8[8];
#pragma unroll
    for (int i = 0; i < 8; ++i)
        a8[i] = __fadd_rn(sm[(ty * 8 + i) * 2], sm[(ty * 8 + i) * 2 + 1]);
    __syncthreads();
    WRITEB(0);

    float v1[8]; int i1[8];
#pragma unroll
    for (int i = 0; i < 8; ++i) { v1[i] = 3.0e38f; i1[i] = 0; }

    int cur = 0;
    for (int cb8 = 0; cb8 < 8; ++cb8) {
        const int cbase = cb8 * TN;

        f2 acc[8][4];
#pragma unroll
        for (int i = 0; i < 8; ++i)
#pragma unroll
            for (int j = 0; j < 4; ++j) acc[i][j] = (f2){0.0f, 0.0f};

        for (int dc8 = 0; dc8 < 8; ++dc8) {
            const int s = cb8 * 8 + dc8;
            __syncthreads();                 // buf[cur] staged & other buf free
            if (s < 63) {
                const int sn = s + 1;
                LOADR((sn >> 3) * TN, (sn & 7) * TD);
            }
            {
                const float* Xc = sm + cur * BSTR;
                const float* Ec = Xc + BUFF;
#pragma unroll 2
                for (int dq = 0; dq < 8; ++dq) {
                    const float* xp0 = Xc + dq * 512 + ((((ty << 1)    ) ^ dq) << 2);
                    const float* xp1 = Xc + dq * 512 + ((((ty << 1) | 1) ^ dq) << 2);
                    const float* ep0 = Ec + dq * 512 + ((tx ^ dq) << 2);
#pragma unroll
                    for (int ddi = 0; ddi < 4; ++ddi) {
                        f4v t0 = *(const f4v*)(xp0 + ddi * 128);   // rows ty*8+0..3, depth d
                        f4v t1 = *(const f4v*)(xp1 + ddi * 128);   // rows ty*8+4..7
                        f4v u0 = *(const f4v*)(ep0 + ddi * 128);   // cols tx*4+0..3
                        f4v u1 = *(const f4v*)(ep0 + ddi * 128 + 64); // cols 64+tx*4..
                        f2 x01 = __builtin_shufflevector(t0, t0, 0, 1);
                        f2 x23 = __builtin_shufflevector(t0, t0, 2, 3);
                        f2 x45 = __builtin_shufflevector(t1, t1, 0, 1);
                        f2 x67 = __builtin_shufflevector(t1, t1, 2, 3);
                        f2 e0  = __builtin_shufflevector(u0, u0, 0, 1);
                        f2 e1  = __builtin_shufflevector(u0, u0, 2, 3);
                        f2 e2  = __builtin_shufflevector(u1, u1, 0, 1);
                        f2 e3  = __builtin_shufflevector(u1, u1, 2, 3);
                        PKL(acc[0][0], x01, e0) PKL(acc[0][1], x01, e1)
                        PKL(acc[0][2], x01, e2) PKL(acc[0][3], x01, e3)
                        PKH(acc[1][0], x01, e0) PKH(acc[1][1], x01, e1)
                        PKH(acc[1][2], x01, e2) PKH(acc[1][3], x01, e3)
                        PKL(acc[2][0], x23, e0) PKL(acc[2][1], x23, e1)
                        PKL(acc[2][2], x23, e2) PKL(acc[2][3], x23, e3)
                        PKH(acc[3][0], x23, e0) PKH(acc[3][1], x23, e1)
                        PKH(acc[3][2], x23, e2) PKH(acc[3][3], x23, e3)
                        PKL(acc[4][0], x45, e0) PKL(acc[4][1], x45, e1)
                        PKL(acc[4][2], x45, e2) PKL(acc[4][3], x45, e3)
                        PKH(acc[5][0], x45, e0) PKH(acc[5][1], x45, e1)
                        PKH(acc[5][2], x45, e2) PKH(acc[5][3], x45, e3)
                        PKL(acc[6][0], x67, e0) PKL(acc[6][1], x67, e1)
                        PKL(acc[6][2], x67, e2) PKL(acc[6][3], x67, e3)
                        PKH(acc[7][0], x67, e0) PKH(acc[7][1], x67, e1)
                        PKH(acc[7][2], x67, e2) PKH(acc[7][3], x67, e3)
                    }
                }
            }
            if (s < 63) WRITEB(cur ^ 1);     // write-late: lands in other buffer
            cur ^= 1;
        }

        // fold this col-block: dist = fl(fl(A + B) - 2*dot), numpy rounding.
        float4 bq0 = *(const float4*)(B32 + cbase + (tx << 2));
        float4 bq1 = *(const float4*)(B32 + cbase + 64 + (tx << 2));
        float bvv[8] = {bq0.x, bq0.y, bq0.z, bq0.w, bq1.x, bq1.y, bq1.z, bq1.w};
#pragma unroll
        for (int j = 0; j < 8; ++j) {
            const int c = cbase + ((j < 4) ? ((tx << 2) + j)
                                           : (64 + (tx << 2) + (j - 4)));
#pragma unroll
            for (int i = 0; i < 8; ++i) {
                float av  = acc[i][j >> 1][j & 1];
                float Cv  = __fmul_rn(2.0f, av);
                float t1v = __fadd_rn(a8[i], bvv[j]);
                float dv  = __fsub_rn(t1v, Cv);
                // strict < keeps first (lowest) index; c ascends per thread
                if (dv < v1[i]) { v1[i] = dv; i1[i] = c; }
            }
        }
    }

    // ---- merge (val, idx) across the 16 col-group threads per row ----
    __syncthreads();
    float* Mv   = sm;                        // [128][16] floats  (bytes 0..8191)
    int*   Mi   = (int*)(sm + 2048);         // [128][16] ints    (8192..16383)
    int*   sIdx = (int*)(sm + 4096);         // [128] final idx   (16384..16895)
    double* wsum = (double*)(sm + 4224);     // [4] doubles       (16896..16927)
#pragma unroll
    for (int i = 0; i < 8; ++i) {
        int r = ty * 8 + i;
        Mv[r * 16 + tx] = v1[i];
        Mi[r * 16 + tx] = i1[i];
    }
    __syncthreads();
    if (tid < TM) {
        int r = tid;
        float bv = Mv[r * 16];
        int   bi = Mi[r * 16];
        for (int t = 1; t < 16; ++t) {
            float av = Mv[r * 16 + t];
            int   ai = Mi[r * 16 + t];
            if (av < bv || (av == bv && ai < bi)) { bv = av; bi = ai; }
        }
        sIdx[r] = bi;
        out1[rowbase + r] = (float)bi;
        atomicAdd(&counts[bi], 1);
    }
    __syncthreads();

    // ---- fused gather + quantized output + fp64 loss ----
    const size_t base = (size_t)rowbase * DIM;
    double s = 0.0;
#pragma unroll 4
    for (int g = 0; g < 32; ++g) {
        int fi  = tid + g * 256;             // 0..8191
        int row = fi >> 6;
        int d4  = fi & 63;
        int j = sIdx[row];
        float4 q = *(const float4*)(E + (size_t)j * DIM + d4 * 4);
        float4 x = *(const float4*)(X + base + (size_t)fi * 4);
        *(float4*)(out0 + base + (size_t)fi * 4) = q;
        double dx;
        dx = (double)q.x - (double)x.x; s = fma(dx, dx, s);
        dx = (double)q.y - (double)x.y; s = fma(dx, dx, s);
        dx = (double)q.z - (double)x.z; s = fma(dx, dx, s);
        dx = (double)q.w - (double)x.w; s = fma(dx, dx, s);
    }
#pragma unroll
    for (int off = 32; off > 0; off >>= 1) s += __shfl_down(s, off, 64);
    int lane = tid & 63, wv = tid >> 6;
    if (lane == 0) wsum[wv] = s;
    __syncthreads();
    if (tid == 0) {
        double t = wsum[0] + wsum[1] + wsum[2] + wsum[3];
        atomicAdd(lossacc, t);
    }
#undef LOADR
#undef WRITE1
#undef WRITEB
}

// ---------------- K4: perplexity + loss finalize ----------------
__global__ void k_fin(const int* __restrict__ counts,
                      const double* __restrict__ lossacc,
                      float* __restrict__ out_pl)
{
    __shared__ double sh[256];
    double s = 0.0;
    for (int i = threadIdx.x; i < KC; i += 256) {
        double p = (double)counts[i] / 65536.0;
        s += p * log(p + 1.1920928955078125e-07);   // EPS = fp32 eps exactly
    }
    sh[threadIdx.x] = s;
    __syncthreads();
    for (int off = 128; off > 0; off >>= 1) {
        if (threadIdx.x < off) sh[threadIdx.x] += sh[threadIdx.x + off];
        __syncthreads();
    }
    if (threadIdx.x == 0) {
        out_pl[0] = (float)exp(-sh[0]);
        out_pl[1] = (float)((*lossacc / (double)NQ) * 1.1);  // q + 0.1*e latent
    }
}

extern "C" void kernel_launch(void* const* d_in, const int* in_sizes, int n_in,
                              void* d_out, int out_size, void* d_ws, size_t ws_size,
                              hipStream_t stream) {
    const float* X = (const float*)d_in[0];
    const float* E = (const float*)d_in[1];
    float* out = (float*)d_out;
    char* ws = (char*)d_ws;

    double* lossacc = (double*)(ws + 0);
    int*    counts  = (int*)(ws + 16);
    float*  B32     = (float*)(ws + 4224);

    // zero lossacc + counts (B32 fully overwritten by k_prepB)
    hipMemsetAsync(d_ws, 0, 4224, stream);

    hipLaunchKernelGGL(k_prepB, dim3(4),         dim3(256), 0, stream, E, B32);
    hipLaunchKernelGGL(k_pass1, dim3(ROWS / TM), dim3(256), 0, stream,
                       X, E, B32, out, out + NQ, counts, lossacc);
    hipLaunchKernelGGL(k_fin,   dim3(1),         dim3(256), 0, stream,
                       counts, lossacc, out + NQ + 65536);
}